// Round 2
// baseline (1090.082 us; speedup 1.0000x reference)
//
#include <hip/hip_runtime.h>
#include <hip/hip_bf16.h>

#define DEPTH 2
#define DIM   1024
#define SDIM  256
#define BATCH 256
#define SHOTS 64
#define M_TOT (BATCH*SHOTS)   // 16384

__device__ __forceinline__ float softplus_f(float x) {
    // log(1 + exp(x)), stable for large x
    if (x > 20.f) return x;
    return log1pf(__expf(x));
}

// ---------------------------------------------------------------------------
// proj_kernel: for one layer, computes
//   P = X @ Wd           (then delta = softplus(P + bd))
//   Q = X @ Wi           (then u     = Q + bi)
//   decay = exp(-delta * softplus(A_log));  drive = delta * u
// X: [M_TOT, DIM] f32;  Wd,Wi: [DIM, SDIM] f32; outputs f32 [M_TOT, SDIM]
// Tiling: 64x64 block tile, 256 threads, 4x4 per thread, BK=16.
// ---------------------------------------------------------------------------
#define BK 16

__global__ __launch_bounds__(256)
void proj_kernel(const float* __restrict__ X,
                 const float* __restrict__ Wd, const float* __restrict__ bd,
                 const float* __restrict__ Wi, const float* __restrict__ bi,
                 const float* __restrict__ A_log,
                 float* __restrict__ decay, float* __restrict__ drive)
{
    __shared__ float Xs[64][BK + 1];
    __shared__ float Wds[BK][64 + 1];
    __shared__ float Wis[BK][64 + 1];

    const int tid  = threadIdx.x;
    const int row0 = blockIdx.x * 64;
    const int col0 = blockIdx.y * 64;
    const int tx = tid & 15;     // n-direction (4 cols each)
    const int ty = tid >> 4;     // m-direction (4 rows each)

    float accP[4][4] = {{0.f}};
    float accQ[4][4] = {{0.f}};

    for (int k0 = 0; k0 < DIM; k0 += BK) {
        // X tile: 64 x 16  (4 elems/thread, coalesced over k within 16 lanes)
        {
            const int kl = tid & (BK - 1);
            const int mb = tid >> 4;
            #pragma unroll
            for (int r = 0; r < 4; ++r) {
                const int m = mb + r * 16;
                Xs[m][kl] = X[(size_t)(row0 + m) * DIM + k0 + kl];
            }
        }
        // W tiles: 16 x 64 (coalesced over n)
        {
            const int nl = tid & 63;
            const int kb = tid >> 6;
            #pragma unroll
            for (int r = 0; r < 4; ++r) {
                const int k = kb + r * 4;
                Wds[k][nl] = Wd[(size_t)(k0 + k) * SDIM + col0 + nl];
                Wis[k][nl] = Wi[(size_t)(k0 + k) * SDIM + col0 + nl];
            }
        }
        __syncthreads();

        #pragma unroll
        for (int kk = 0; kk < BK; ++kk) {
            float a[4], wd4[4], wi4[4];
            #pragma unroll
            for (int i = 0; i < 4; ++i) a[i] = Xs[ty * 4 + i][kk];
            #pragma unroll
            for (int j = 0; j < 4; ++j) {
                wd4[j] = Wds[kk][tx * 4 + j];
                wi4[j] = Wis[kk][tx * 4 + j];
            }
            #pragma unroll
            for (int i = 0; i < 4; ++i)
                #pragma unroll
                for (int j = 0; j < 4; ++j) {
                    accP[i][j] += a[i] * wd4[j];
                    accQ[i][j] += a[i] * wi4[j];
                }
        }
        __syncthreads();
    }

    #pragma unroll
    for (int j = 0; j < 4; ++j) {
        const int n = col0 + tx * 4 + j;
        const float bdv = bd[n];
        const float biv = bi[n];
        const float spA = softplus_f(A_log[n]);
        #pragma unroll
        for (int i = 0; i < 4; ++i) {
            const int m = row0 + ty * 4 + i;
            const float delta = softplus_f(accP[i][j] + bdv);
            const float u     = accQ[i][j] + biv;
            const size_t idx  = (size_t)m * SDIM + n;
            decay[idx] = __expf(-delta * spA);
            drive[idx] = delta * u;
        }
    }
}

// ---------------------------------------------------------------------------
// scan_kernel: h[s] = decay[s]*h[s-1] + drive[s] over SHOTS, per (b,n).
// One block per b, one thread per n (coalesced over n every step).
// ---------------------------------------------------------------------------
__global__ __launch_bounds__(SDIM)
void scan_kernel(const float* __restrict__ decay, const float* __restrict__ drive,
                 float* __restrict__ hs, float* __restrict__ state)
{
    const int b = blockIdx.x;
    const int n = threadIdx.x;
    float h = 0.f;
    for (int s = 0; s < SHOTS; ++s) {
        const size_t idx = ((size_t)(b * SHOTS + s)) * SDIM + n;
        h = decay[idx] * h + drive[idx];
        hs[idx] = h;
    }
    state[(size_t)b * SDIM + n] = h;
}

// ---------------------------------------------------------------------------
// cs_kernel: class_state[b,d] = state[b,:] @ Ws[:,d] + bs[d]
// grid (BATCH, DIM/256), block 256. state row staged in LDS.
// ---------------------------------------------------------------------------
__global__ __launch_bounds__(256)
void cs_kernel(const float* __restrict__ state, const float* __restrict__ Ws,
               const float* __restrict__ bs, float* __restrict__ cs)
{
    __shared__ float sst[SDIM];
    const int b = blockIdx.x;
    const int d = blockIdx.y * 256 + threadIdx.x;
    sst[threadIdx.x] = state[(size_t)b * SDIM + threadIdx.x];
    __syncthreads();
    float acc = 0.f;
    for (int n = 0; n < SDIM; ++n)
        acc += sst[n] * Ws[(size_t)n * DIM + d];
    cs[(size_t)b * DIM + d] = acc + bs[d];
}

// ---------------------------------------------------------------------------
// y_kernel: hidden[m,d] = hs[m,:] @ Wo[:,d] + bo[d] + class_state[m/SHOTS, d]
// hs f32 [M_TOT, SDIM]; Wo f32 [SDIM, DIM]; out f32 [M_TOT, DIM].
// Same 64x64 tiling as proj.
// ---------------------------------------------------------------------------
__global__ __launch_bounds__(256)
void y_kernel(const float* __restrict__ hs, const float* __restrict__ Wo,
              const float* __restrict__ bo, const float* __restrict__ cs,
              float* __restrict__ out)
{
    __shared__ float As[64][BK + 1];
    __shared__ float Bs[BK][64 + 1];

    const int tid  = threadIdx.x;
    const int row0 = blockIdx.x * 64;
    const int col0 = blockIdx.y * 64;
    const int tx = tid & 15;
    const int ty = tid >> 4;

    float acc[4][4] = {{0.f}};

    for (int k0 = 0; k0 < SDIM; k0 += BK) {
        {
            const int kl = tid & (BK - 1);
            const int mb = tid >> 4;
            #pragma unroll
            for (int r = 0; r < 4; ++r) {
                const int m = mb + r * 16;
                As[m][kl] = hs[(size_t)(row0 + m) * SDIM + k0 + kl];
            }
        }
        {
            const int nl = tid & 63;
            const int kb = tid >> 6;
            #pragma unroll
            for (int r = 0; r < 4; ++r) {
                const int k = kb + r * 4;
                Bs[k][nl] = Wo[(size_t)(k0 + k) * DIM + col0 + nl];
            }
        }
        __syncthreads();

        #pragma unroll
        for (int kk = 0; kk < BK; ++kk) {
            float a[4], w4[4];
            #pragma unroll
            for (int i = 0; i < 4; ++i) a[i] = As[ty * 4 + i][kk];
            #pragma unroll
            for (int j = 0; j < 4; ++j) w4[j] = Bs[kk][tx * 4 + j];
            #pragma unroll
            for (int i = 0; i < 4; ++i)
                #pragma unroll
                for (int j = 0; j < 4; ++j)
                    acc[i][j] += a[i] * w4[j];
        }
        __syncthreads();
    }

    #pragma unroll
    for (int i = 0; i < 4; ++i) {
        const int m = row0 + ty * 4 + i;
        const int b = m >> 6;  // m / SHOTS
        #pragma unroll
        for (int j = 0; j < 4; ++j) {
            const int n = col0 + tx * 4 + j;
            out[(size_t)m * DIM + n] = acc[i][j] + bo[n] + cs[(size_t)b * DIM + n];
        }
    }
}

// ---------------------------------------------------------------------------
// final_kernel: pooled = class_state + mean_s(hidden); LayerNorm -> class_repr
// grid BATCH, block 256 (each thread owns 4 d's, strided by 256).
// ---------------------------------------------------------------------------
__global__ __launch_bounds__(256)
void final_kernel(const float* __restrict__ hidden, const float* __restrict__ cs,
                  const float* __restrict__ gamma, const float* __restrict__ beta,
                  float* __restrict__ out)
{
    const int b   = blockIdx.x;
    const int tid = threadIdx.x;

    float pooled[4];
    float lsum = 0.f, lsq = 0.f;
    #pragma unroll
    for (int j = 0; j < 4; ++j) {
        const int d = tid + j * 256;
        float acc = 0.f;
        for (int s = 0; s < SHOTS; ++s)
            acc += hidden[((size_t)(b * SHOTS + s)) * DIM + d];
        const float p = cs[(size_t)b * DIM + d] + acc * (1.f / SHOTS);
        pooled[j] = p;
        lsum += p;
        lsq  += p * p;
    }

    __shared__ float rsum[256], rsq[256];
    rsum[tid] = lsum; rsq[tid] = lsq;
    __syncthreads();
    for (int off = 128; off > 0; off >>= 1) {
        if (tid < off) { rsum[tid] += rsum[tid + off]; rsq[tid] += rsq[tid + off]; }
        __syncthreads();
    }
    const float mu  = rsum[0] * (1.f / DIM);
    const float var = rsq[0] * (1.f / DIM) - mu * mu;
    const float inv = rsqrtf(var + 1e-5f);

    #pragma unroll
    for (int j = 0; j < 4; ++j) {
        const int d = tid + j * 256;
        out[(size_t)b * DIM + d] =
            (pooled[j] - mu) * inv * gamma[d] + beta[d];
    }
}

// ---------------------------------------------------------------------------

extern "C" void kernel_launch(void* const* d_in, const int* in_sizes, int n_in,
                              void* d_out, int out_size, void* d_ws, size_t ws_size,
                              hipStream_t stream)
{
    const float* X0    = (const float*)d_in[0];
    const float* Wd    = (const float*)d_in[1];
    const float* bd    = (const float*)d_in[2];
    const float* Wi    = (const float*)d_in[3];
    const float* bi    = (const float*)d_in[4];
    const float* A_log = (const float*)d_in[5];
    const float* Wo    = (const float*)d_in[6];
    const float* bo    = (const float*)d_in[7];
    const float* Ws    = (const float*)d_in[8];
    const float* bs    = (const float*)d_in[9];
    const float* gamma = (const float*)d_in[10];
    const float* beta  = (const float*)d_in[11];

    float* out_cr     = (float*)d_out;                      // [BATCH, DIM]
    float* out_hidden = out_cr + (size_t)BATCH * DIM;       // [BATCH, SHOTS, DIM]

    // ws layout (f32), reused across layers: ~49.4 MB total
    float* ws    = (float*)d_ws;
    float* decay = ws;                                      // M_TOT*SDIM
    float* drive = decay + (size_t)M_TOT * SDIM;            // M_TOT*SDIM
    float* hsbuf = drive + (size_t)M_TOT * SDIM;            // M_TOT*SDIM
    float* state = hsbuf + (size_t)M_TOT * SDIM;            // BATCH*SDIM
    float* csbuf = state + (size_t)BATCH * SDIM;            // BATCH*DIM

    for (int l = 0; l < DEPTH; ++l) {
        const float* Xl = (l == 0) ? X0 : out_hidden;  // layer-1 hidden staged in d_out
        proj_kernel<<<dim3(M_TOT / 64, SDIM / 64), 256, 0, stream>>>(
            Xl,
            Wd + (size_t)l * DIM * SDIM, bd + l * SDIM,
            Wi + (size_t)l * DIM * SDIM, bi + l * SDIM,
            A_log + l * SDIM, decay, drive);
        scan_kernel<<<BATCH, SDIM, 0, stream>>>(decay, drive, hsbuf, state);
        cs_kernel<<<dim3(BATCH, DIM / 256), 256, 0, stream>>>(
            state, Ws + (size_t)l * SDIM * DIM, bs + l * DIM, csbuf);
        y_kernel<<<dim3(M_TOT / 64, DIM / 64), 256, 0, stream>>>(
            hsbuf, Wo + (size_t)l * SDIM * DIM, bo + l * DIM, csbuf, out_hidden);
    }
    final_kernel<<<BATCH, 256, 0, stream>>>(out_hidden, csbuf, gamma, beta, out_cr);
}

// Round 3
// 424.092 us; speedup vs baseline: 2.5704x; 2.5704x over previous
//
#include <hip/hip_runtime.h>

#define DEPTH 2
#define DIM   1024
#define SDIM  256
#define BATCH 256
#define SHOTS 64
#define M_TOT (BATCH*SHOTS)   // 16384

typedef __attribute__((ext_vector_type(8))) short bf16x8;  // 8 bf16 = 4 VGPRs
typedef __attribute__((ext_vector_type(4))) float f32x4;
typedef unsigned short u16;

__device__ __forceinline__ u16 f2bf(float f) {
    // round-to-nearest-even fp32 -> bf16 (no NaN inputs in this problem)
    union { float f; unsigned u; } v; v.f = f;
    unsigned r = v.u + 0x7fffu + ((v.u >> 16) & 1u);
    return (u16)(r >> 16);
}

__device__ __forceinline__ float softplus_f(float x) {
    if (x > 20.f) return x;
    return log1pf(__expf(x));
}

// ---------------------------------------------------------------------------
// transpose_conv: out[n][k] (bf16) = in[k][n] (fp32), dual-source split over n.
// For WcombT: A1=Wd [K,SPLIT], A2=Wi [K,N-SPLIT]. For WoT: SPLIT=N (A1 only).
// grid (K/64, N/64, DEPTH), block 256. LDS tile transpose, coalesced both ways.
// ---------------------------------------------------------------------------
__global__ __launch_bounds__(256)
void transpose_conv(const float* __restrict__ A1, const float* __restrict__ A2,
                    u16* __restrict__ out, int K, int N, int SPLIT)
{
    __shared__ float T[64][65];
    const int layer = blockIdx.z;
    const int k0 = blockIdx.x * 64, n0 = blockIdx.y * 64;
    const int tid = threadIdx.x;

    const bool first = (n0 < SPLIT);
    const int scols = first ? SPLIT : (N - SPLIT);
    const float* S = (first ? A1 : A2) + (size_t)layer * K * scols
                     + (first ? n0 : (n0 - SPLIT));
    out += (size_t)layer * K * N;

    #pragma unroll
    for (int i = 0; i < 4; ++i) {
        const int c = tid + i * 256;
        const int kr = c >> 4, cc = c & 15;
        const float4 v = *(const float4*)(S + (size_t)(k0 + kr) * scols + cc * 4);
        T[kr][cc * 4 + 0] = v.x; T[kr][cc * 4 + 1] = v.y;
        T[kr][cc * 4 + 2] = v.z; T[kr][cc * 4 + 3] = v.w;
    }
    __syncthreads();
    #pragma unroll
    for (int i = 0; i < 4; ++i) {
        const int c = tid + i * 256;
        const int nr = c >> 4, cc = c & 15;
        ushort4 h;
        h.x = f2bf(T[cc * 4 + 0][nr]); h.y = f2bf(T[cc * 4 + 1][nr]);
        h.z = f2bf(T[cc * 4 + 2][nr]); h.w = f2bf(T[cc * 4 + 3][nr]);
        *(ushort4*)&out[(size_t)(n0 + nr) * K + k0 + cc * 4] = h;
    }
}

// ---------------------------------------------------------------------------
// gemm_mfma: C[M,N] = A[M,K] @ BT[N,K]^T with bf16 MFMA (16x16x32).
// 128x128 block tile, BK=32, 256 threads = 4 waves in 2x2, each wave 64x64
// (4x4 subtiles, 16 MFMA / K-chunk). LDS rows padded 32->40 bf16 so the
// ds_read_b128 fragment loads are <=2-way (free) on the 32 banks.
// A_F32: A is fp32, converted to bf16 during staging (saves an X_bf16 pass).
// EPI_Y: epilogue adds bo[n] + cs[row/64][n].
// Grid is flat with an XCD swizzle: all CB col-blocks of a row-block land on
// the same XCD (id%8) so the A slab is read once per XCD L2, not CB times.
// ---------------------------------------------------------------------------
#define BM 128
#define BN 128
#define BKT 32
#define LSTR 40   // padded LDS row stride, bf16 units (80 B, multiple of 16)

template<bool A_F32, bool EPI_Y>
__global__ __launch_bounds__(256)
void gemm_mfma(const void* __restrict__ Av, const u16* __restrict__ BT,
               float* __restrict__ C, const float* __restrict__ bo,
               const float* __restrict__ cs, int K, int ldc, int CB)
{
    __shared__ __align__(16) u16 As[BM * LSTR];
    __shared__ __align__(16) u16 Bs[BN * LSTR];

    const int tid = threadIdx.x;
    const int id  = blockIdx.x;
    const int xcd = id & 7, slot = id >> 3;
    const int rb  = xcd + 8 * (slot / CB);
    const int cb  = slot % CB;
    const int row0 = rb * BM, col0 = cb * BN;

    const int l  = tid & 63;
    const int w  = tid >> 6;
    const int wm = (w >> 1) * 64, wn = (w & 1) * 64;
    const int lr = l & 15, lq = l >> 4;

    f32x4 acc[4][4];
    #pragma unroll
    for (int i = 0; i < 4; ++i)
        #pragma unroll
        for (int j = 0; j < 4; ++j)
            acc[i][j] = (f32x4){0.f, 0.f, 0.f, 0.f};

    for (int k0 = 0; k0 < K; k0 += BKT) {
        if (A_F32) {
            const float* A = (const float*)Av;
            #pragma unroll
            for (int i = 0; i < 4; ++i) {
                const int c = tid + i * 256;           // 1024 float4 chunks
                const int row = c >> 3, kc = c & 7;
                const float4 v = *(const float4*)(A + (size_t)(row0 + row) * K + k0 + kc * 4);
                ushort4 h;
                h.x = f2bf(v.x); h.y = f2bf(v.y); h.z = f2bf(v.z); h.w = f2bf(v.w);
                *(ushort4*)&As[row * LSTR + kc * 4] = h;
            }
        } else {
            const u16* A = (const u16*)Av;
            #pragma unroll
            for (int i = 0; i < 2; ++i) {
                const int c = tid + i * 256;           // 512 16B chunks
                const int row = c >> 2, kc = c & 3;
                *(int4*)&As[row * LSTR + kc * 8] =
                    *(const int4*)(A + (size_t)(row0 + row) * K + k0 + kc * 8);
            }
        }
        #pragma unroll
        for (int i = 0; i < 2; ++i) {
            const int c = tid + i * 256;
            const int row = c >> 2, kc = c & 3;
            *(int4*)&Bs[row * LSTR + kc * 8] =
                *(const int4*)(BT + (size_t)(col0 + row) * K + k0 + kc * 8);
        }
        __syncthreads();

        bf16x8 af[4], bfr[4];
        #pragma unroll
        for (int i = 0; i < 4; ++i)
            af[i] = *(const bf16x8*)&As[(wm + i * 16 + lr) * LSTR + lq * 8];
        #pragma unroll
        for (int j = 0; j < 4; ++j)
            bfr[j] = *(const bf16x8*)&Bs[(wn + j * 16 + lr) * LSTR + lq * 8];

        #pragma unroll
        for (int i = 0; i < 4; ++i)
            #pragma unroll
            for (int j = 0; j < 4; ++j)
                acc[i][j] = __builtin_amdgcn_mfma_f32_16x16x32_bf16(
                    af[i], bfr[j], acc[i][j], 0, 0, 0);
        __syncthreads();
    }

    // epilogue: C/D layout col=lane&15, row=quad*4+reg (m89/m91 verified)
    #pragma unroll
    for (int i = 0; i < 4; ++i) {
        const int grow = row0 + wm + i * 16 + lq * 4;   // 4-aligned, same batch for +0..3
        #pragma unroll
        for (int j = 0; j < 4; ++j) {
            const int gcol = col0 + wn + j * 16 + lr;
            float addv = 0.f;
            if (EPI_Y) addv = bo[gcol] + cs[(size_t)(grow >> 6) * DIM + gcol];
            #pragma unroll
            for (int r = 0; r < 4; ++r)
                C[(size_t)(grow + r) * ldc + gcol] = acc[i][j][r] + addv;
        }
    }
}

// ---------------------------------------------------------------------------
// scan_cs_kernel: per (b,n): delta=softplus(P+bd), u=Q+bi,
//   h = exp(-delta*softplus(A_log))*h + delta*u over SHOTS; hs -> bf16.
// Then (state already in the block): class_state[b,:] = state @ Ws + bs.
// PQ: [M_TOT, 512] fp32 (P cols 0..255, Q cols 256..511).
// ---------------------------------------------------------------------------
__global__ __launch_bounds__(256)
void scan_cs_kernel(const float* __restrict__ PQ,
                    const float* __restrict__ bd, const float* __restrict__ bi,
                    const float* __restrict__ A_log,
                    const float* __restrict__ Ws, const float* __restrict__ bs,
                    u16* __restrict__ hsb, float* __restrict__ csbuf)
{
    __shared__ float sst[SDIM];
    const int b = blockIdx.x, n = threadIdx.x;
    const float bdv = bd[n], biv = bi[n];
    const float spA = softplus_f(A_log[n]);
    float h = 0.f;
    for (int s = 0; s < SHOTS; ++s) {
        const size_t base = (size_t)(b * SHOTS + s) * (2 * SDIM);
        const float P = PQ[base + n];
        const float Q = PQ[base + SDIM + n];
        const float delta = softplus_f(P + bdv);
        const float dec = __expf(-delta * spA);
        h = dec * h + delta * (Q + biv);
        hsb[(size_t)(b * SHOTS + s) * SDIM + n] = f2bf(h);
    }
    sst[n] = h;
    __syncthreads();
    #pragma unroll
    for (int j = 0; j < 4; ++j) {
        const int d = n + j * 256;
        float acc = 0.f;
        for (int k = 0; k < SDIM; ++k)
            acc += sst[k] * Ws[(size_t)k * DIM + d];
        csbuf[(size_t)b * DIM + d] = acc + bs[d];
    }
}

// ---------------------------------------------------------------------------
// final_kernel: pooled = class_state + mean_s(hidden); LayerNorm.
// ---------------------------------------------------------------------------
__global__ __launch_bounds__(256)
void final_kernel(const float* __restrict__ hidden, const float* __restrict__ cs,
                  const float* __restrict__ gamma, const float* __restrict__ beta,
                  float* __restrict__ out)
{
    const int b   = blockIdx.x;
    const int tid = threadIdx.x;

    float pooled[4];
    float lsum = 0.f, lsq = 0.f;
    #pragma unroll
    for (int j = 0; j < 4; ++j) {
        const int d = tid + j * 256;
        float acc = 0.f;
        for (int s = 0; s < SHOTS; ++s)
            acc += hidden[((size_t)(b * SHOTS + s)) * DIM + d];
        const float p = cs[(size_t)b * DIM + d] + acc * (1.f / SHOTS);
        pooled[j] = p;
        lsum += p;
        lsq  += p * p;
    }

    __shared__ float rsum[256], rsq[256];
    rsum[tid] = lsum; rsq[tid] = lsq;
    __syncthreads();
    for (int off = 128; off > 0; off >>= 1) {
        if (tid < off) { rsum[tid] += rsum[tid + off]; rsq[tid] += rsq[tid + off]; }
        __syncthreads();
    }
    const float mu  = rsum[0] * (1.f / DIM);
    const float var = rsq[0] * (1.f / DIM) - mu * mu;
    const float inv = rsqrtf(var + 1e-5f);

    #pragma unroll
    for (int j = 0; j < 4; ++j) {
        const int d = tid + j * 256;
        out[(size_t)b * DIM + d] = (pooled[j] - mu) * inv * gamma[d] + beta[d];
    }
}

// ---------------------------------------------------------------------------

extern "C" void kernel_launch(void* const* d_in, const int* in_sizes, int n_in,
                              void* d_out, int out_size, void* d_ws, size_t ws_size,
                              hipStream_t stream)
{
    const float* X0    = (const float*)d_in[0];
    const float* Wd    = (const float*)d_in[1];
    const float* bd    = (const float*)d_in[2];
    const float* Wi    = (const float*)d_in[3];
    const float* bi    = (const float*)d_in[4];
    const float* A_log = (const float*)d_in[5];
    const float* Wo    = (const float*)d_in[6];
    const float* bo    = (const float*)d_in[7];
    const float* Ws    = (const float*)d_in[8];
    const float* bs    = (const float*)d_in[9];
    const float* gamma = (const float*)d_in[10];
    const float* beta  = (const float*)d_in[11];

    float* out_cr     = (float*)d_out;                  // [BATCH, DIM]
    float* out_hidden = out_cr + (size_t)BATCH * DIM;   // [BATCH, SHOTS, DIM] fp32

    // ws layout: ~46.4 MB (<= 49.4 MB proven safe in round 1)
    char* w = (char*)d_ws;
    float* PQ     = (float*)w;  w += (size_t)M_TOT * 512 * 4;          // 33.55 MB
    float* csbuf  = (float*)w;  w += (size_t)BATCH * DIM * 4;          //  1.05 MB
    u16*   hsb    = (u16*)w;    w += (size_t)M_TOT * SDIM * 2;         //  8.39 MB
    u16*   WcombT = (u16*)w;    w += (size_t)DEPTH * 512 * 1024 * 2;   //  2.10 MB
    u16*   WoT    = (u16*)w;    w += (size_t)DEPTH * 1024 * 256 * 2;   //  1.05 MB

    // one-time weight transpose+convert (both layers via grid.z)
    transpose_conv<<<dim3(1024 / 64, 512 / 64, DEPTH), 256, 0, stream>>>(
        Wd, Wi, WcombT, 1024, 512, 256);
    transpose_conv<<<dim3(256 / 64, 1024 / 64, DEPTH), 256, 0, stream>>>(
        Wo, Wo, WoT, 256, 1024, 1024);

    for (int l = 0; l < DEPTH; ++l) {
        const float* Xl = (l == 0) ? X0 : out_hidden;
        // PQ = X @ [Wd|Wi]  (M=16384, N=512, K=1024), fp32 A staged->bf16
        gemm_mfma<true, false><<<512, 256, 0, stream>>>(
            Xl, WcombT + (size_t)l * 512 * 1024, PQ, nullptr, nullptr,
            1024, 512, 4);
        // selective scan + class_state GEMM
        scan_cs_kernel<<<BATCH, 256, 0, stream>>>(
            PQ, bd + l * SDIM, bi + l * SDIM, A_log + l * SDIM,
            Ws + (size_t)l * SDIM * DIM, bs + l * DIM, hsb, csbuf);
        // hidden = hs @ Wo + bo + class_state  (M=16384, N=1024, K=256)
        gemm_mfma<false, true><<<1024, 256, 0, stream>>>(
            hsb, WoT + (size_t)l * 1024 * 256, out_hidden, bo + l * DIM, csbuf,
            256, 1024, 8);
    }
    final_kernel<<<BATCH, 256, 0, stream>>>(out_hidden, csbuf, gamma, beta, out_cr);
}

// Round 4
// 368.564 us; speedup vs baseline: 2.9576x; 1.1507x over previous
//
#include <hip/hip_runtime.h>

#define DEPTH 2
#define DIM   1024
#define SDIM  256
#define BATCH 256
#define SHOTS 64
#define M_TOT (BATCH*SHOTS)   // 16384
#define NCH   8               // scan chunks
#define CH    (SHOTS/NCH)     // 8 steps per chunk

typedef __attribute__((ext_vector_type(8))) short bf16x8;  // 8 bf16 = 4 VGPRs
typedef __attribute__((ext_vector_type(4))) float f32x4;
typedef unsigned short u16;

__device__ __forceinline__ u16 f2bf(float f) {
    union { float f; unsigned u; } v; v.f = f;
    unsigned r = v.u + 0x7fffu + ((v.u >> 16) & 1u);
    return (u16)(r >> 16);
}

__device__ __forceinline__ float softplus_f(float x) {
    if (x > 20.f) return x;
    return log1pf(__expf(x));
}

// ---------------------------------------------------------------------------
// transpose_conv: out[n][k] (bf16) = in[k][n] (fp32), dual-source split over n.
// ---------------------------------------------------------------------------
__global__ __launch_bounds__(256)
void transpose_conv(const float* __restrict__ A1, const float* __restrict__ A2,
                    u16* __restrict__ out, int K, int N, int SPLIT)
{
    __shared__ float T[64][65];
    const int layer = blockIdx.z;
    const int k0 = blockIdx.x * 64, n0 = blockIdx.y * 64;
    const int tid = threadIdx.x;

    const bool first = (n0 < SPLIT);
    const int scols = first ? SPLIT : (N - SPLIT);
    const float* S = (first ? A1 : A2) + (size_t)layer * K * scols
                     + (first ? n0 : (n0 - SPLIT));
    out += (size_t)layer * K * N;

    #pragma unroll
    for (int i = 0; i < 4; ++i) {
        const int c = tid + i * 256;
        const int kr = c >> 4, cc = c & 15;
        const float4 v = *(const float4*)(S + (size_t)(k0 + kr) * scols + cc * 4);
        T[kr][cc * 4 + 0] = v.x; T[kr][cc * 4 + 1] = v.y;
        T[kr][cc * 4 + 2] = v.z; T[kr][cc * 4 + 3] = v.w;
    }
    __syncthreads();
    #pragma unroll
    for (int i = 0; i < 4; ++i) {
        const int c = tid + i * 256;
        const int nr = c >> 4, cc = c & 15;
        ushort4 h;
        h.x = f2bf(T[cc * 4 + 0][nr]); h.y = f2bf(T[cc * 4 + 1][nr]);
        h.z = f2bf(T[cc * 4 + 2][nr]); h.w = f2bf(T[cc * 4 + 3][nr]);
        *(ushort4*)&out[(size_t)(n0 + nr) * K + k0 + cc * 4] = h;
    }
}

#define BM 128
#define BN 128
#define BKT 32
#define LSTR 40   // padded LDS row stride (bf16 units): 80 B -> 2-way banks (free)

// ---------------------------------------------------------------------------
// gemm_pq: dual-GEMM P = X@Wd, Q = X@Wi over the SAME A tile, fused epilogue
//   delta = softplus(P+bd); dg[m][n] = { exp(-delta*softplus(A_log)),
//                                        delta*(Q+bi) }
// X fp32 [M_TOT,1024] -> bf16 in staging. WdT/WiT bf16 [256,1024].
// Grid flat 256: RB=128 row-blocks x CB=2 col-blocks, XCD swizzle.
// ---------------------------------------------------------------------------
__global__ __launch_bounds__(256, 1)
void gemm_pq(const float* __restrict__ X,
             const u16* __restrict__ WdT, const u16* __restrict__ WiT,
             const float* __restrict__ bd, const float* __restrict__ bi,
             const float* __restrict__ A_log, float2* __restrict__ dg)
{
    __shared__ __align__(16) u16 As[BM * LSTR];
    __shared__ __align__(16) u16 Bds[BN * LSTR];
    __shared__ __align__(16) u16 Bis[BN * LSTR];

    const int tid = threadIdx.x;
    const int id  = blockIdx.x;
    const int xcd = id & 7, slot = id >> 3;
    const int rb  = xcd + 8 * (slot >> 1);
    const int cb  = slot & 1;
    const int row0 = rb * BM, col0 = cb * BN;

    const int l  = tid & 63;
    const int w  = tid >> 6;
    const int wm = (w >> 1) * 64, wn = (w & 1) * 64;
    const int lr = l & 15, lq = l >> 4;

    f32x4 accP[4][4], accQ[4][4];
    #pragma unroll
    for (int i = 0; i < 4; ++i)
        #pragma unroll
        for (int j = 0; j < 4; ++j) {
            accP[i][j] = (f32x4){0.f, 0.f, 0.f, 0.f};
            accQ[i][j] = (f32x4){0.f, 0.f, 0.f, 0.f};
        }

    for (int k0 = 0; k0 < DIM; k0 += BKT) {
        #pragma unroll
        for (int i = 0; i < 4; ++i) {
            const int c = tid + i * 256;            // 1024 float4 chunks
            const int row = c >> 3, kc = c & 7;
            const float4 v = *(const float4*)(X + (size_t)(row0 + row) * DIM + k0 + kc * 4);
            ushort4 h;
            h.x = f2bf(v.x); h.y = f2bf(v.y); h.z = f2bf(v.z); h.w = f2bf(v.w);
            *(ushort4*)&As[row * LSTR + kc * 4] = h;
        }
        #pragma unroll
        for (int i = 0; i < 2; ++i) {
            const int c = tid + i * 256;            // 512 16B chunks per tile
            const int row = c >> 2, kc = c & 3;
            *(int4*)&Bds[row * LSTR + kc * 8] =
                *(const int4*)(WdT + (size_t)(col0 + row) * DIM + k0 + kc * 8);
            *(int4*)&Bis[row * LSTR + kc * 8] =
                *(const int4*)(WiT + (size_t)(col0 + row) * DIM + k0 + kc * 8);
        }
        __syncthreads();

        bf16x8 af[4], bd4[4], bi4[4];
        #pragma unroll
        for (int i = 0; i < 4; ++i)
            af[i] = *(const bf16x8*)&As[(wm + i * 16 + lr) * LSTR + lq * 8];
        #pragma unroll
        for (int j = 0; j < 4; ++j) {
            bd4[j] = *(const bf16x8*)&Bds[(wn + j * 16 + lr) * LSTR + lq * 8];
            bi4[j] = *(const bf16x8*)&Bis[(wn + j * 16 + lr) * LSTR + lq * 8];
        }

        #pragma unroll
        for (int i = 0; i < 4; ++i)
            #pragma unroll
            for (int j = 0; j < 4; ++j) {
                accP[i][j] = __builtin_amdgcn_mfma_f32_16x16x32_bf16(
                    af[i], bd4[j], accP[i][j], 0, 0, 0);
                accQ[i][j] = __builtin_amdgcn_mfma_f32_16x16x32_bf16(
                    af[i], bi4[j], accQ[i][j], 0, 0, 0);
            }
        __syncthreads();
    }

    // epilogue: C/D layout col=lane&15, row=quad*4+reg
    #pragma unroll
    for (int j = 0; j < 4; ++j) {
        const int n = ((col0 + wn + j * 16 + lr) & (SDIM - 1));  // col0+... < 256
        const float bdv = bd[n], biv = bi[n];
        const float spA = softplus_f(A_log[n]);
        #pragma unroll
        for (int i = 0; i < 4; ++i) {
            const int grow = row0 + wm + i * 16 + lq * 4;
            #pragma unroll
            for (int r = 0; r < 4; ++r) {
                const float delta = softplus_f(accP[i][j][r] + bdv);
                const float dec = __expf(-delta * spA);
                const float drv = delta * (accQ[i][j][r] + biv);
                dg[(size_t)(grow + r) * SDIM + n] = make_float2(dec, drv);
            }
        }
    }
}

// ---------------------------------------------------------------------------
// gemm_mfma: C[M,N] = A[M,K] @ BT[N,K]^T, bf16 MFMA. EPI: 0=none, 1=+bias,
// 2=+bias+cs[row/64]. SWIZ: XCD swizzle (needs grid multiple of 8*CB).
// ---------------------------------------------------------------------------
template<bool A_F32, int EPI, bool SWIZ>
__global__ __launch_bounds__(256)
void gemm_mfma(const void* __restrict__ Av, const u16* __restrict__ BT,
               float* __restrict__ C, const float* __restrict__ bo,
               const float* __restrict__ cs, int K, int ldc, int CB)
{
    __shared__ __align__(16) u16 As[BM * LSTR];
    __shared__ __align__(16) u16 Bs[BN * LSTR];

    const int tid = threadIdx.x;
    const int id  = blockIdx.x;
    int rb, cb;
    if (SWIZ) {
        const int xcd = id & 7, slot = id >> 3;
        rb = xcd + 8 * (slot / CB);
        cb = slot % CB;
    } else {
        rb = id / CB; cb = id % CB;
    }
    const int row0 = rb * BM, col0 = cb * BN;

    const int l  = tid & 63;
    const int w  = tid >> 6;
    const int wm = (w >> 1) * 64, wn = (w & 1) * 64;
    const int lr = l & 15, lq = l >> 4;

    f32x4 acc[4][4];
    #pragma unroll
    for (int i = 0; i < 4; ++i)
        #pragma unroll
        for (int j = 0; j < 4; ++j)
            acc[i][j] = (f32x4){0.f, 0.f, 0.f, 0.f};

    for (int k0 = 0; k0 < K; k0 += BKT) {
        if (A_F32) {
            const float* A = (const float*)Av;
            #pragma unroll
            for (int i = 0; i < 4; ++i) {
                const int c = tid + i * 256;
                const int row = c >> 3, kc = c & 7;
                const float4 v = *(const float4*)(A + (size_t)(row0 + row) * K + k0 + kc * 4);
                ushort4 h;
                h.x = f2bf(v.x); h.y = f2bf(v.y); h.z = f2bf(v.z); h.w = f2bf(v.w);
                *(ushort4*)&As[row * LSTR + kc * 4] = h;
            }
        } else {
            const u16* A = (const u16*)Av;
            #pragma unroll
            for (int i = 0; i < 2; ++i) {
                const int c = tid + i * 256;
                const int row = c >> 2, kc = c & 3;
                *(int4*)&As[row * LSTR + kc * 8] =
                    *(const int4*)(A + (size_t)(row0 + row) * K + k0 + kc * 8);
            }
        }
        #pragma unroll
        for (int i = 0; i < 2; ++i) {
            const int c = tid + i * 256;
            const int row = c >> 2, kc = c & 3;
            *(int4*)&Bs[row * LSTR + kc * 8] =
                *(const int4*)(BT + (size_t)(col0 + row) * K + k0 + kc * 8);
        }
        __syncthreads();

        bf16x8 af[4], bfr[4];
        #pragma unroll
        for (int i = 0; i < 4; ++i)
            af[i] = *(const bf16x8*)&As[(wm + i * 16 + lr) * LSTR + lq * 8];
        #pragma unroll
        for (int j = 0; j < 4; ++j)
            bfr[j] = *(const bf16x8*)&Bs[(wn + j * 16 + lr) * LSTR + lq * 8];

        #pragma unroll
        for (int i = 0; i < 4; ++i)
            #pragma unroll
            for (int j = 0; j < 4; ++j)
                acc[i][j] = __builtin_amdgcn_mfma_f32_16x16x32_bf16(
                    af[i], bfr[j], acc[i][j], 0, 0, 0);
        __syncthreads();
    }

    #pragma unroll
    for (int i = 0; i < 4; ++i) {
        const int grow = row0 + wm + i * 16 + lq * 4;
        #pragma unroll
        for (int j = 0; j < 4; ++j) {
            const int gcol = col0 + wn + j * 16 + lr;
            float addv = 0.f;
            if (EPI >= 1) addv += bo[gcol];
            if (EPI == 2) addv += cs[(size_t)(grow >> 6) * DIM + gcol];
            #pragma unroll
            for (int r = 0; r < 4; ++r)
                C[(size_t)(grow + r) * ldc + gcol] = acc[i][j][r] + addv;
        }
    }
}

// ---------------------------------------------------------------------------
// scan_phaseA: per (b, chunk c, n): compose 8 steps -> (prod_decay, h_from_0)
// ---------------------------------------------------------------------------
__global__ __launch_bounds__(256)
void scan_phaseA(const float2* __restrict__ dg, float2* __restrict__ sums)
{
    const int b = blockIdx.x, c = blockIdx.y, n = threadIdx.x;
    const size_t base = ((size_t)b * SHOTS + c * CH) * SDIM + n;
    float a = 1.f, h = 0.f;
    #pragma unroll
    for (int s = 0; s < CH; ++s) {
        const float2 v = dg[base + (size_t)s * SDIM];
        a *= v.x;
        h = v.x * h + v.y;
    }
    sums[((size_t)b * NCH + c) * SDIM + n] = make_float2(a, h);
}

// ---------------------------------------------------------------------------
// scan_phaseC: compose prefix from chunk summaries, replay 8 steps, write hs
// (bf16) and final state (chunk NCH-1).
// ---------------------------------------------------------------------------
__global__ __launch_bounds__(256)
void scan_phaseC(const float2* __restrict__ dg, const float2* __restrict__ sums,
                 u16* __restrict__ hsb, float* __restrict__ state)
{
    const int b = blockIdx.x, c = blockIdx.y, n = threadIdx.x;
    float h = 0.f;
    for (int j = 0; j < c; ++j) {
        const float2 sv = sums[((size_t)b * NCH + j) * SDIM + n];
        h = sv.x * h + sv.y;
    }
    const size_t base = ((size_t)b * SHOTS + c * CH) * SDIM + n;
    #pragma unroll
    for (int s = 0; s < CH; ++s) {
        const float2 v = dg[base + (size_t)s * SDIM];
        h = v.x * h + v.y;
        hsb[base + (size_t)s * SDIM] = f2bf(h);
    }
    if (c == NCH - 1) state[(size_t)b * SDIM + n] = h;
}

// ---------------------------------------------------------------------------
// final_kernel: pooled = class_state + mean_s(hidden); LayerNorm.
// 1024 threads (one per d) -> 16 waves/CU for the 67 MB read.
// ---------------------------------------------------------------------------
__global__ __launch_bounds__(1024)
void final_kernel(const float* __restrict__ hidden, const float* __restrict__ cs,
                  const float* __restrict__ gamma, const float* __restrict__ beta,
                  float* __restrict__ out)
{
    const int b = blockIdx.x;
    const int d = threadIdx.x;

    float acc = 0.f;
    #pragma unroll 4
    for (int s = 0; s < SHOTS; ++s)
        acc += hidden[((size_t)(b * SHOTS + s)) * DIM + d];
    const float p = cs[(size_t)b * DIM + d] + acc * (1.f / SHOTS);

    __shared__ float rsum[1024], rsq[1024];
    rsum[d] = p; rsq[d] = p * p;
    __syncthreads();
    for (int off = 512; off > 0; off >>= 1) {
        if (d < off) { rsum[d] += rsum[d + off]; rsq[d] += rsq[d + off]; }
        __syncthreads();
    }
    const float mu  = rsum[0] * (1.f / DIM);
    const float var = rsq[0] * (1.f / DIM) - mu * mu;
    const float inv = rsqrtf(var + 1e-5f);

    out[(size_t)b * DIM + d] = (p - mu) * inv * gamma[d] + beta[d];
}

// ---------------------------------------------------------------------------

extern "C" void kernel_launch(void* const* d_in, const int* in_sizes, int n_in,
                              void* d_out, int out_size, void* d_ws, size_t ws_size,
                              hipStream_t stream)
{
    const float* X0    = (const float*)d_in[0];
    const float* Wd    = (const float*)d_in[1];
    const float* bd    = (const float*)d_in[2];
    const float* Wi    = (const float*)d_in[3];
    const float* bi    = (const float*)d_in[4];
    const float* A_log = (const float*)d_in[5];
    const float* Wo    = (const float*)d_in[6];
    const float* bo    = (const float*)d_in[7];
    const float* Ws    = (const float*)d_in[8];
    const float* bs    = (const float*)d_in[9];
    const float* gamma = (const float*)d_in[10];
    const float* beta  = (const float*)d_in[11];

    float* out_cr     = (float*)d_out;                  // [BATCH, DIM]
    float* out_hidden = out_cr + (size_t)BATCH * DIM;   // [BATCH, SHOTS, DIM] fp32

    // ws layout: 51,642,368 B == round-1 proven footprint
    char* w = (char*)d_ws;
    float2* DG     = (float2*)w; w += (size_t)M_TOT * SDIM * 8;         // 33.55 MB
    float2* sums   = (float2*)w; w += (size_t)BATCH * NCH * SDIM * 8;   //  4.19 MB
    float*  csbuf  = (float*)w;  w += (size_t)BATCH * DIM * 4;          //  1.05 MB
    float*  state  = (float*)w;  w += (size_t)BATCH * SDIM * 4;         //  0.26 MB
    u16*    hsb    = (u16*)w;    w += (size_t)M_TOT * SDIM * 2;         //  8.39 MB
    u16*    WcombT = (u16*)w;    w += (size_t)DEPTH * 512 * 1024 * 2;   //  2.10 MB
    u16*    WoT    = (u16*)w;    w += (size_t)DEPTH * 1024 * 256 * 2;   //  1.05 MB
    u16*    WsT    = (u16*)w;    w += (size_t)DEPTH * 1024 * 256 * 2;   //  1.05 MB

    // one-time weight transpose+convert
    transpose_conv<<<dim3(1024 / 64, 512 / 64, DEPTH), 256, 0, stream>>>(
        Wd, Wi, WcombT, 1024, 512, 256);   // rows 0-255: WdT, 256-511: WiT
    transpose_conv<<<dim3(256 / 64, 1024 / 64, DEPTH), 256, 0, stream>>>(
        Wo, Wo, WoT, 256, 1024, 1024);
    transpose_conv<<<dim3(256 / 64, 1024 / 64, DEPTH), 256, 0, stream>>>(
        Ws, Ws, WsT, 256, 1024, 1024);

    for (int l = 0; l < DEPTH; ++l) {
        const float* Xl = (l == 0) ? X0 : out_hidden;
        const u16* WdT = WcombT + (size_t)l * 512 * 1024;
        const u16* WiT = WdT + (size_t)256 * 1024;
        // P,Q dual-GEMM + decay/drive epilogue
        gemm_pq<<<256, 256, 0, stream>>>(
            Xl, WdT, WiT, bd + l * SDIM, bi + l * SDIM, A_log + l * SDIM, DG);
        // chunked scan
        scan_phaseA<<<dim3(BATCH, NCH), SDIM, 0, stream>>>(DG, sums);
        scan_phaseC<<<dim3(BATCH, NCH), SDIM, 0, stream>>>(DG, sums, hsb, state);
        // class_state = state @ Ws + bs  (M=256, N=1024, K=256)
        gemm_mfma<true, 1, false><<<16, 256, 0, stream>>>(
            state, WsT + (size_t)l * 1024 * 256, csbuf, bs + l * DIM, nullptr,
            256, 1024, 8);
        // hidden = hs @ Wo + bo + class_state  (M=16384, N=1024, K=256)
        gemm_mfma<false, 2, true><<<1024, 256, 0, stream>>>(
            hsb, WoT + (size_t)l * 1024 * 256, out_hidden, bo + l * DIM, csbuf,
            256, 1024, 8);
    }
    final_kernel<<<BATCH, 1024, 0, stream>>>(out_hidden, csbuf, gamma, beta, out_cr);
}

// Round 5
// 359.752 us; speedup vs baseline: 3.0301x; 1.0245x over previous
//
#include <hip/hip_runtime.h>
#include <hip/hip_bf16.h>

#define DEPTH 2
#define DIM   1024
#define SDIM  256
#define BATCH 256
#define SHOTS 64
#define M_TOT (BATCH*SHOTS)   // 16384
#define NCH   8               // scan chunks
#define CH    (SHOTS/NCH)     // 8 steps per chunk

typedef __attribute__((ext_vector_type(8))) short bf16x8;  // 8 bf16 = 4 VGPRs
typedef __attribute__((ext_vector_type(4))) float f32x4;
typedef unsigned short u16;

__device__ __forceinline__ u16 f2bf(float f) {
    union { float f; unsigned u; } v; v.f = f;
    unsigned r = v.u + 0x7fffu + ((v.u >> 16) & 1u);
    return (u16)(r >> 16);
}

__device__ __forceinline__ unsigned pk_bf2(float a, float b) {
    union { __hip_bfloat162 h2; unsigned u; } c;
    c.h2 = __float22bfloat162_rn(make_float2(a, b));   // v_cvt_pk_bf16_f32
    return c.u;
}

__device__ __forceinline__ float softplus_f(float x) {
    if (x > 20.f) return x;
    return log1pf(__expf(x));
}

// ---------------------------------------------------------------------------
// transpose_conv: out[n][k] (bf16) = in[k][n] (fp32), dual-source split over n.
// ---------------------------------------------------------------------------
__global__ __launch_bounds__(256)
void transpose_conv(const float* __restrict__ A1, const float* __restrict__ A2,
                    u16* __restrict__ out, int K, int N, int SPLIT)
{
    __shared__ float T[64][65];
    const int layer = blockIdx.z;
    const int k0 = blockIdx.x * 64, n0 = blockIdx.y * 64;
    const int tid = threadIdx.x;

    const bool first = (n0 < SPLIT);
    const int scols = first ? SPLIT : (N - SPLIT);
    const float* S = (first ? A1 : A2) + (size_t)layer * K * scols
                     + (first ? n0 : (n0 - SPLIT));
    out += (size_t)layer * K * N;

    #pragma unroll
    for (int i = 0; i < 4; ++i) {
        const int c = tid + i * 256;
        const int kr = c >> 4, cc = c & 15;
        const float4 v = *(const float4*)(S + (size_t)(k0 + kr) * scols + cc * 4);
        T[kr][cc * 4 + 0] = v.x; T[kr][cc * 4 + 1] = v.y;
        T[kr][cc * 4 + 2] = v.z; T[kr][cc * 4 + 3] = v.w;
    }
    __syncthreads();
    #pragma unroll
    for (int i = 0; i < 4; ++i) {
        const int c = tid + i * 256;
        const int nr = c >> 4, cc = c & 15;
        ushort4 h;
        h.x = f2bf(T[cc * 4 + 0][nr]); h.y = f2bf(T[cc * 4 + 1][nr]);
        h.z = f2bf(T[cc * 4 + 2][nr]); h.w = f2bf(T[cc * 4 + 3][nr]);
        *(ushort4*)&out[(size_t)(n0 + nr) * K + k0 + cc * 4] = h;
    }
}

#define BM 128
#define BN 128
#define BKT 32
#define LSTR 40   // padded LDS row stride (bf16 units): 80 B -> 2-way banks

// ---------------------------------------------------------------------------
// gemm_mfma: C[M,N] = A[M,K] @ BT[N,K]^T, bf16 MFMA 16x16x32.
// 128x128 tile, 4 waves 2x2, 4x4 subtiles each. A_F32: packed-convert fp32
// A while staging. EPI: 0 none, 1 +bias, 2 +bias+cs[row/64]. SWIZ: XCD.
// ---------------------------------------------------------------------------
template<bool A_F32, int EPI, bool SWIZ>
__global__ __launch_bounds__(256)
void gemm_mfma(const void* __restrict__ Av, const u16* __restrict__ BT,
               float* __restrict__ C, const float* __restrict__ bo,
               const float* __restrict__ cs, int K, int ldc, int CB)
{
    __shared__ __align__(16) u16 As[BM * LSTR];
    __shared__ __align__(16) u16 Bs[BN * LSTR];

    const int tid = threadIdx.x;
    const int id  = blockIdx.x;
    int rb, cb;
    if (SWIZ) {
        const int xcd = id & 7, slot = id >> 3;
        rb = xcd + 8 * (slot / CB);
        cb = slot % CB;
    } else {
        rb = id / CB; cb = id % CB;
    }
    const int row0 = rb * BM, col0 = cb * BN;

    const int l  = tid & 63;
    const int w  = tid >> 6;
    const int wm = (w >> 1) * 64, wn = (w & 1) * 64;
    const int lr = l & 15, lq = l >> 4;

    f32x4 acc[4][4];
    #pragma unroll
    for (int i = 0; i < 4; ++i)
        #pragma unroll
        for (int j = 0; j < 4; ++j)
            acc[i][j] = (f32x4){0.f, 0.f, 0.f, 0.f};

    for (int k0 = 0; k0 < K; k0 += BKT) {
        if (A_F32) {
            const float* A = (const float*)Av;
            #pragma unroll
            for (int i = 0; i < 4; ++i) {
                const int c = tid + i * 256;
                const int row = c >> 3, kc = c & 7;
                const float4 v = *(const float4*)(A + (size_t)(row0 + row) * K + k0 + kc * 4);
                const uint2 pk = make_uint2(pk_bf2(v.x, v.y), pk_bf2(v.z, v.w));
                *(uint2*)&As[row * LSTR + kc * 4] = pk;
            }
        } else {
            const u16* A = (const u16*)Av;
            #pragma unroll
            for (int i = 0; i < 2; ++i) {
                const int c = tid + i * 256;
                const int row = c >> 2, kc = c & 3;
                *(int4*)&As[row * LSTR + kc * 8] =
                    *(const int4*)(A + (size_t)(row0 + row) * K + k0 + kc * 8);
            }
        }
        #pragma unroll
        for (int i = 0; i < 2; ++i) {
            const int c = tid + i * 256;
            const int row = c >> 2, kc = c & 3;
            *(int4*)&Bs[row * LSTR + kc * 8] =
                *(const int4*)(BT + (size_t)(col0 + row) * K + k0 + kc * 8);
        }
        __syncthreads();

        bf16x8 af[4], bfr[4];
        #pragma unroll
        for (int i = 0; i < 4; ++i)
            af[i] = *(const bf16x8*)&As[(wm + i * 16 + lr) * LSTR + lq * 8];
        #pragma unroll
        for (int j = 0; j < 4; ++j)
            bfr[j] = *(const bf16x8*)&Bs[(wn + j * 16 + lr) * LSTR + lq * 8];

        #pragma unroll
        for (int i = 0; i < 4; ++i)
            #pragma unroll
            for (int j = 0; j < 4; ++j)
                acc[i][j] = __builtin_amdgcn_mfma_f32_16x16x32_bf16(
                    af[i], bfr[j], acc[i][j], 0, 0, 0);
        __syncthreads();
    }

    // epilogue: C/D layout col=lane&15, row=quad*4+reg
    #pragma unroll
    for (int i = 0; i < 4; ++i) {
        const int grow = row0 + wm + i * 16 + lq * 4;
        #pragma unroll
        for (int j = 0; j < 4; ++j) {
            const int gcol = col0 + wn + j * 16 + lr;
            float addv = 0.f;
            if (EPI >= 1) addv += bo[gcol];
            if (EPI == 2) addv += cs[(size_t)(grow >> 6) * DIM + gcol];
            #pragma unroll
            for (int r = 0; r < 4; ++r)
                C[(size_t)(grow + r) * ldc + gcol] = acc[i][j][r] + addv;
        }
    }
}

// ---------------------------------------------------------------------------
// scan_phaseA: per (b, chunk c, n): read raw P,Q; compute dec/drv inline;
// compose 8 steps -> (prod_decay, h_from_zero_state).
// PQ: [M_TOT, 512] fp32 (P = cols 0..255, Q = cols 256..511).
// ---------------------------------------------------------------------------
__global__ __launch_bounds__(256)
void scan_phaseA(const float* __restrict__ PQ,
                 const float* __restrict__ bd, const float* __restrict__ bi,
                 const float* __restrict__ A_log, float2* __restrict__ sums)
{
    const int b = blockIdx.x, c = blockIdx.y, n = threadIdx.x;
    const float bdv = bd[n], biv = bi[n];
    const float spA = softplus_f(A_log[n]);
    const size_t m0 = (size_t)b * SHOTS + c * CH;
    float a = 1.f, h = 0.f;
    #pragma unroll
    for (int s = 0; s < CH; ++s) {
        const float* row = PQ + (m0 + s) * 512;
        const float delta = softplus_f(row[n] + bdv);
        const float dec = __expf(-delta * spA);
        const float drv = delta * (row[n + SDIM] + biv);
        a *= dec;
        h = dec * h + drv;
    }
    sums[((size_t)b * NCH + c) * SDIM + n] = make_float2(a, h);
}

// ---------------------------------------------------------------------------
// scan_phaseC: compose prefix from chunk summaries, replay 8 steps (recompute
// dec/drv), write hs (bf16) and final state (last chunk).
// ---------------------------------------------------------------------------
__global__ __launch_bounds__(256)
void scan_phaseC(const float* __restrict__ PQ, const float2* __restrict__ sums,
                 const float* __restrict__ bd, const float* __restrict__ bi,
                 const float* __restrict__ A_log,
                 u16* __restrict__ hsb, float* __restrict__ state)
{
    const int b = blockIdx.x, c = blockIdx.y, n = threadIdx.x;
    const float bdv = bd[n], biv = bi[n];
    const float spA = softplus_f(A_log[n]);
    float h = 0.f;
    for (int j = 0; j < c; ++j) {
        const float2 sv = sums[((size_t)b * NCH + j) * SDIM + n];
        h = sv.x * h + sv.y;
    }
    const size_t m0 = (size_t)b * SHOTS + c * CH;
    #pragma unroll
    for (int s = 0; s < CH; ++s) {
        const float* row = PQ + (m0 + s) * 512;
        const float delta = softplus_f(row[n] + bdv);
        const float dec = __expf(-delta * spA);
        const float drv = delta * (row[n + SDIM] + biv);
        h = dec * h + drv;
        hsb[(m0 + s) * SDIM + n] = f2bf(h);
    }
    if (c == NCH - 1) state[(size_t)b * SDIM + n] = h;
}

// ---------------------------------------------------------------------------
// final_kernel: pooled = class_state + mean_s(hidden); LayerNorm.
// ---------------------------------------------------------------------------
__global__ __launch_bounds__(1024)
void final_kernel(const float* __restrict__ hidden, const float* __restrict__ cs,
                  const float* __restrict__ gamma, const float* __restrict__ beta,
                  float* __restrict__ out)
{
    const int b = blockIdx.x;
    const int d = threadIdx.x;

    float acc = 0.f;
    #pragma unroll 4
    for (int s = 0; s < SHOTS; ++s)
        acc += hidden[((size_t)(b * SHOTS + s)) * DIM + d];
    const float p = cs[(size_t)b * DIM + d] + acc * (1.f / SHOTS);

    __shared__ float rsum[1024], rsq[1024];
    rsum[d] = p; rsq[d] = p * p;
    __syncthreads();
    for (int off = 512; off > 0; off >>= 1) {
        if (d < off) { rsum[d] += rsum[d + off]; rsq[d] += rsq[d + off]; }
        __syncthreads();
    }
    const float mu  = rsum[0] * (1.f / DIM);
    const float var = rsq[0] * (1.f / DIM) - mu * mu;
    const float inv = rsqrtf(var + 1e-5f);

    out[(size_t)b * DIM + d] = (p - mu) * inv * gamma[d] + beta[d];
}

// ---------------------------------------------------------------------------

extern "C" void kernel_launch(void* const* d_in, const int* in_sizes, int n_in,
                              void* d_out, int out_size, void* d_ws, size_t ws_size,
                              hipStream_t stream)
{
    const float* X0    = (const float*)d_in[0];
    const float* Wd    = (const float*)d_in[1];
    const float* bd    = (const float*)d_in[2];
    const float* Wi    = (const float*)d_in[3];
    const float* bi    = (const float*)d_in[4];
    const float* A_log = (const float*)d_in[5];
    const float* Wo    = (const float*)d_in[6];
    const float* bo    = (const float*)d_in[7];
    const float* Ws    = (const float*)d_in[8];
    const float* bs    = (const float*)d_in[9];
    const float* gamma = (const float*)d_in[10];
    const float* beta  = (const float*)d_in[11];

    float* out_cr     = (float*)d_out;                  // [BATCH, DIM]
    float* out_hidden = out_cr + (size_t)BATCH * DIM;   // [BATCH, SHOTS, DIM] fp32

    // ws layout: 51,642,368 B == proven footprint (rounds 1/3/4)
    char* w = (char*)d_ws;
    float*  PQ     = (float*)w;  w += (size_t)M_TOT * 512 * 4;          // 33.55 MB
    float2* sums   = (float2*)w; w += (size_t)BATCH * NCH * SDIM * 8;   //  4.19 MB
    float*  csbuf  = (float*)w;  w += (size_t)BATCH * DIM * 4;          //  1.05 MB
    float*  state  = (float*)w;  w += (size_t)BATCH * SDIM * 4;         //  0.26 MB
    u16*    hsb    = (u16*)w;    w += (size_t)M_TOT * SDIM * 2;         //  8.39 MB
    u16*    WcombT = (u16*)w;    w += (size_t)DEPTH * 512 * 1024 * 2;   //  2.10 MB
    u16*    WoT    = (u16*)w;    w += (size_t)DEPTH * 1024 * 256 * 2;   //  1.05 MB
    u16*    WsT    = (u16*)w;    w += (size_t)DEPTH * 1024 * 256 * 2;   //  1.05 MB

    // one-time weight transpose+convert
    transpose_conv<<<dim3(1024 / 64, 512 / 64, DEPTH), 256, 0, stream>>>(
        Wd, Wi, WcombT, 1024, 512, 256);   // rows 0-255: WdT, 256-511: WiT
    transpose_conv<<<dim3(256 / 64, 1024 / 64, DEPTH), 256, 0, stream>>>(
        Wo, Wo, WoT, 256, 1024, 1024);
    transpose_conv<<<dim3(256 / 64, 1024 / 64, DEPTH), 256, 0, stream>>>(
        Ws, Ws, WsT, 256, 1024, 1024);

    for (int l = 0; l < DEPTH; ++l) {
        const float* Xl = (l == 0) ? X0 : out_hidden;
        // PQ = X @ [Wd|Wi]  (M=16384, N=512, K=1024): grid 512 -> 2 blocks/CU
        gemm_mfma<true, 0, true><<<512, 256, 0, stream>>>(
            Xl, WcombT + (size_t)l * 512 * 1024, PQ, nullptr, nullptr,
            1024, 512, 4);
        // chunked scan with inline decay/drive
        scan_phaseA<<<dim3(BATCH, NCH), SDIM, 0, stream>>>(
            PQ, bd + l * SDIM, bi + l * SDIM, A_log + l * SDIM, sums);
        scan_phaseC<<<dim3(BATCH, NCH), SDIM, 0, stream>>>(
            PQ, sums, bd + l * SDIM, bi + l * SDIM, A_log + l * SDIM, hsb, state);
        // class_state = state @ Ws + bs  (M=256, N=1024, K=256)
        gemm_mfma<true, 1, false><<<16, 256, 0, stream>>>(
            state, WsT + (size_t)l * 1024 * 256, csbuf, bs + l * DIM, nullptr,
            256, 1024, 8);
        // hidden = hs @ Wo + bo + class_state  (M=16384, N=1024, K=256)
        gemm_mfma<false, 2, true><<<1024, 256, 0, stream>>>(
            hsb, WoT + (size_t)l * 1024 * 256, out_hidden, bo + l * DIM, csbuf,
            256, 1024, 8);
    }
    final_kernel<<<BATCH, 1024, 0, stream>>>(out_hidden, csbuf, gamma, beta, out_cr);
}